// Round 3
// baseline (330.356 us; speedup 1.0000x reference)
//
// GroupedSubMConv3d conv_main v2.1 — burst-gather restructure (resubmit, cache-bust)
#include <hip/hip_runtime.h>
#include <hip/hip_fp16.h>

#define NVOX 400000
#define KVOL 27
#define CTOT 64
#define NTILES (NVOX / 16)     // 25000 exact
#define NPAIR 14               // 27 offsets -> 14 pairs (last padded)
#define WFRAG_HALVES (4 * NPAIR * 64 * 8)   // 28672 f16 = 57344 B

// ---------------- ws layout ----------------
// featH : _Float16[NVOX*64]   offset 0           (51,200,000 B)
// wfrag : _Float16[28672]     offset 51,200,000  (57,344 B)
#define FEATH_OFF 0
#define WFRAG_OFF 51200000

typedef __attribute__((ext_vector_type(8))) _Float16 half8;
typedef __attribute__((ext_vector_type(4))) float float4v;

// feat fp32 -> fp16, 8 elements per thread
__global__ void cvt_feat_kernel(const float* __restrict__ f, _Float16* __restrict__ fh) {
    int t = blockIdx.x * blockDim.x + threadIdx.x;
    const int total = NVOX * CTOT / 8;   // 3,200,000 threads
    if (t >= total) return;
    const float4* fp = (const float4*)f + (size_t)t * 2;
    float4 a = fp[0], b = fp[1];
    union { _Float16 h[8]; uint4 u; } r;
    r.h[0] = (_Float16)a.x; r.h[1] = (_Float16)a.y;
    r.h[2] = (_Float16)a.z; r.h[3] = (_Float16)a.w;
    r.h[4] = (_Float16)b.x; r.h[5] = (_Float16)b.y;
    r.h[6] = (_Float16)b.z; r.h[7] = (_Float16)b.w;
    ((uint4*)fh)[t] = r.u;
}

// weight[g][ko][ci][co] fp32 -> B-fragment layout f16:
// wfrag[g][p][lane][j] = w[g][2p + (quad>>1)][ci=(quad&1)*8+j][co=lane&15], quad=lane>>4
// ko >= 27 (padded pair) -> 0.0, giving a guaranteed-zero 512B region per group
__global__ void cvt_w_kernel(const float* __restrict__ w, _Float16* __restrict__ wf) {
    int t = blockIdx.x * blockDim.x + threadIdx.x;
    if (t >= WFRAG_HALVES) return;
    int j = t & 7;
    int l = (t >> 3) & 63;
    int gp = t >> 9;            // 0..55
    int p = gp % NPAIR;
    int g = gp / NPAIR;
    int co = l & 15;
    int quad = l >> 4;
    int ko = 2 * p + (quad >> 1);
    int ci = (quad & 1) * 8 + j;
    float val = (ko < KVOL) ? w[((g * KVOL + ko) * 16 + ci) * 16 + co] : 0.f;
    wf[t] = (_Float16)val;
}

__global__ __launch_bounds__(256) void conv_main_kernel(
        const _Float16* __restrict__ fh,
        const uint4*    __restrict__ wfrag,
        const float*    __restrict__ bias,
        const int*      __restrict__ nb,
        float* __restrict__ out) {
    __shared__ int s_nb[16 * 28];        // [v][k], k padded to 28 with -1
    const int tile = blockIdx.x;
    const int t = threadIdx.x;

    // coalesced nb stage: 432 contiguous dwords for this tile's 16 voxels
    const int* src = nb + (size_t)tile * (16 * KVOL);
    for (int j = t; j < 16 * KVOL; j += 256) {
        int v = j / KVOL;
        int k = j - v * KVOL;
        s_nb[v * 28 + k] = src[j];
    }
    if (t < 16) s_nb[t * 28 + 27] = -1;

    const int lane = t & 63;
    const int g = t >> 6;                // wave index = group
    const int v = lane & 15;             // voxel within tile (A-frag row m)
    const int quad = lane >> 4;
    const int q2 = quad >> 1;            // which offset of the pair
    const int half = quad & 1;           // which 8-ci half

    // B-fragments resident in registers (56 regs), loaded coalesced once.
    // Issued before the barrier so they overlap the nb stage.
    uint4 wB[NPAIR];
#pragma unroll
    for (int p = 0; p < NPAIR; ++p)
        wB[p] = wfrag[(g * NPAIR + p) * 64 + lane];

    __syncthreads();

    // ---- burst 1: all 14 neighbor indices (14x ds_read_b32, pipelined) ----
    int idx[NPAIR];
#pragma unroll
    for (int p = 0; p < NPAIR; ++p)
        idx[p] = s_nb[v * 28 + 2 * p + q2];

    const _Float16* fbase = fh + g * 16 + half * 8;
    // 512B of guaranteed zeros: wfrag[g=0][p=13][lanes 32..63] has ko=27 -> 0
    // halves index ((0*14+13)*64 + 32)*8 = 6912, byte offset 13824 (16B aligned)
    const _Float16* zp = (const _Float16*)wfrag + 6912;

    // ---- burst 2: issue all 14 scattered gathers back-to-back ----
    // inactive lanes read the zero page (address select, no data masking)
    uint4 a[NPAIR];
#pragma unroll
    for (int p = 0; p < NPAIR; ++p) {
        const _Float16* rp = (idx[p] >= 0) ? (fbase + (size_t)idx[p] * CTOT) : zp;
        a[p] = *(const uint4*)rp;
    }
    // keep all 14 loads issued before any MFMA (prevents re-sinking to save regs)
    __builtin_amdgcn_sched_barrier(0);

    // ---- MFMA phase: two independent accumulator chains ----
    float4v acc0 = {0.f, 0.f, 0.f, 0.f};
    float4v acc1 = {0.f, 0.f, 0.f, 0.f};
#pragma unroll
    for (int p = 0; p < NPAIR; p += 2) {
        acc0 = __builtin_amdgcn_mfma_f32_16x16x32_f16(
            __builtin_bit_cast(half8, a[p]),
            __builtin_bit_cast(half8, wB[p]), acc0, 0, 0, 0);
        acc1 = __builtin_amdgcn_mfma_f32_16x16x32_f16(
            __builtin_bit_cast(half8, a[p + 1]),
            __builtin_bit_cast(half8, wB[p + 1]), acc1, 0, 0, 0);
    }

    // C/D layout: col(co) = lane&15, row(voxel) = quad*4 + r
    const int co = lane & 15;
    const float breg = bias[g * 16 + co];
    float* ob = out + ((size_t)(tile * 16 + quad * 4)) * CTOT + g * 16 + co;
#pragma unroll
    for (int r = 0; r < 4; ++r)
        ob[(size_t)r * CTOT] = acc0[r] + acc1[r] + breg;
}

extern "C" void kernel_launch(void* const* d_in, const int* in_sizes, int n_in,
                              void* d_out, int out_size, void* d_ws, size_t ws_size,
                              hipStream_t stream) {
    const float* features = (const float*)d_in[0];
    const float* weight   = (const float*)d_in[1];
    const float* bias     = (const float*)d_in[2];
    const int*   nb       = (const int*)d_in[3];
    float* out = (float*)d_out;

    char* ws = (char*)d_ws;
    _Float16* featH = (_Float16*)(ws + FEATH_OFF);
    _Float16* wf    = (_Float16*)(ws + WFRAG_OFF);

    cvt_feat_kernel<<<(NVOX * CTOT / 8 + 255) / 256, 256, 0, stream>>>(features, featH);
    cvt_w_kernel<<<(WFRAG_HALVES + 255) / 256, 256, 0, stream>>>(weight, wf);
    conv_main_kernel<<<NTILES, 256, 0, stream>>>(featH, (const uint4*)wf, bias, nb, out);
}

// Round 5
// 310.944 us; speedup vs baseline: 1.0624x; 1.0624x over previous
//
// GroupedSubMConv3d conv_main v3.1 — masked gathers + persistent 10-tile blocks (resubmit)
#include <hip/hip_runtime.h>
#include <hip/hip_fp16.h>

#define NVOX 400000
#define KVOL 27
#define CTOT 64
#define NTILES (NVOX / 16)     // 25000 exact
#define NPAIR 14               // 27 offsets -> 14 pairs (last padded)
#define TILES_PER_BLOCK 10
#define NBLOCKS (NTILES / TILES_PER_BLOCK)   // 2500 exact
#define WFRAG_HALVES (4 * NPAIR * 64 * 8)    // 28672 f16 = 57344 B

// ---------------- ws layout ----------------
// featH : _Float16[NVOX*64]   offset 0           (51,200,000 B)
// wfrag : _Float16[28672]     offset 51,200,000  (57,344 B)
#define FEATH_OFF 0
#define WFRAG_OFF 51200000

typedef __attribute__((ext_vector_type(8))) _Float16 half8;
typedef __attribute__((ext_vector_type(4))) float float4v;

// feat fp32 -> fp16, 8 elements per thread
__global__ void cvt_feat_kernel(const float* __restrict__ f, _Float16* __restrict__ fh) {
    int t = blockIdx.x * blockDim.x + threadIdx.x;
    const int total = NVOX * CTOT / 8;   // 3,200,000 threads
    if (t >= total) return;
    const float4* fp = (const float4*)f + (size_t)t * 2;
    float4 a = fp[0], b = fp[1];
    union { _Float16 h[8]; uint4 u; } r;
    r.h[0] = (_Float16)a.x; r.h[1] = (_Float16)a.y;
    r.h[2] = (_Float16)a.z; r.h[3] = (_Float16)a.w;
    r.h[4] = (_Float16)b.x; r.h[5] = (_Float16)b.y;
    r.h[6] = (_Float16)b.z; r.h[7] = (_Float16)b.w;
    ((uint4*)fh)[t] = r.u;
}

// weight[g][ko][ci][co] fp32 -> B-fragment layout f16:
// wfrag[g][p][lane][j] = w[g][2p + (quad>>1)][ci=(quad&1)*8+j][co=lane&15], quad=lane>>4
// ko >= 27 (padded pair) -> 0.0 (keeps pair-13 second slot inert)
__global__ void cvt_w_kernel(const float* __restrict__ w, _Float16* __restrict__ wf) {
    int t = blockIdx.x * blockDim.x + threadIdx.x;
    if (t >= WFRAG_HALVES) return;
    int j = t & 7;
    int l = (t >> 3) & 63;
    int gp = t >> 9;            // 0..55
    int p = gp % NPAIR;
    int g = gp / NPAIR;
    int co = l & 15;
    int quad = l >> 4;
    int ko = 2 * p + (quad >> 1);
    int ci = (quad & 1) * 8 + j;
    float val = (ko < KVOL) ? w[((g * KVOL + ko) * 16 + ci) * 16 + co] : 0.f;
    wf[t] = (_Float16)val;
}

__global__ __launch_bounds__(256) void conv_main_kernel(
        const _Float16* __restrict__ fh,
        const uint4*    __restrict__ wfrag,
        const float*    __restrict__ bias,
        const int*      __restrict__ nb,
        float* __restrict__ out) {
    __shared__ int s_nb[16 * 28];        // [v][k], k padded to 28 with -1
    const int t = threadIdx.x;
    const int lane = t & 63;
    const int g = t >> 6;                // wave index = group
    const int v = lane & 15;             // voxel within tile (A-frag row m)
    const int quad = lane >> 4;
    const int q2 = quad >> 1;            // which offset of the pair
    const int half = quad & 1;           // which 8-ci half
    const int co = lane & 15;

    // B-fragments resident in registers, loaded ONCE per block (amortized 10x)
    uint4 wB[NPAIR];
#pragma unroll
    for (int p = 0; p < NPAIR; ++p)
        wB[p] = wfrag[(g * NPAIR + p) * 64 + lane];

    const _Float16* fbase = fh + g * 16 + half * 8;
    const float breg = bias[g * 16 + co];

    const int tile0 = blockIdx.x * TILES_PER_BLOCK;
    for (int tt = 0; tt < TILES_PER_BLOCK; ++tt) {
        const int tile = tile0 + tt;

        // protect s_nb against overwrite while prev tile's waves still read it
        __syncthreads();
        const int* src = nb + (size_t)tile * (16 * KVOL);
        for (int j = t; j < 16 * KVOL; j += 256) {
            int vv = j / KVOL;
            int k = j - vv * KVOL;
            s_nb[vv * 28 + k] = src[j];
        }
        if (t < 16) s_nb[t * 28 + 27] = -1;
        __syncthreads();

        // all 14 neighbor indices up front
        int idx[NPAIR];
#pragma unroll
        for (int p = 0; p < NPAIR; ++p)
            idx[p] = s_nb[v * 28 + 2 * p + q2];

        // exec-masked gathers: inactive lanes issue/return NOTHING
        // (zero-init then guarded load; compiler can't speculate -> saveexec mask)
        uint4 a[NPAIR];
#pragma unroll
        for (int p = 0; p < NPAIR; ++p) {
            uint4 z = {0u, 0u, 0u, 0u};
            a[p] = z;
            if (idx[p] >= 0)
                a[p] = *(const uint4*)(fbase + (size_t)idx[p] * CTOT);
        }
        // keep all loads issued before any MFMA
        __builtin_amdgcn_sched_barrier(0);

        // two independent accumulator chains
        float4v acc0 = {0.f, 0.f, 0.f, 0.f};
        float4v acc1 = {0.f, 0.f, 0.f, 0.f};
#pragma unroll
        for (int p = 0; p < NPAIR; p += 2) {
            acc0 = __builtin_amdgcn_mfma_f32_16x16x32_f16(
                __builtin_bit_cast(half8, a[p]),
                __builtin_bit_cast(half8, wB[p]), acc0, 0, 0, 0);
            acc1 = __builtin_amdgcn_mfma_f32_16x16x32_f16(
                __builtin_bit_cast(half8, a[p + 1]),
                __builtin_bit_cast(half8, wB[p + 1]), acc1, 0, 0, 0);
        }

        // C/D layout: col(co) = lane&15, row(voxel) = quad*4 + r
        float* ob = out + ((size_t)(tile * 16 + quad * 4)) * CTOT + g * 16 + co;
#pragma unroll
        for (int r = 0; r < 4; ++r)
            ob[(size_t)r * CTOT] = acc0[r] + acc1[r] + breg;
    }
}

extern "C" void kernel_launch(void* const* d_in, const int* in_sizes, int n_in,
                              void* d_out, int out_size, void* d_ws, size_t ws_size,
                              hipStream_t stream) {
    const float* features = (const float*)d_in[0];
    const float* weight   = (const float*)d_in[1];
    const float* bias     = (const float*)d_in[2];
    const int*   nb       = (const int*)d_in[3];
    float* out = (float*)d_out;

    char* ws = (char*)d_ws;
    _Float16* featH = (_Float16*)(ws + FEATH_OFF);
    _Float16* wf    = (_Float16*)(ws + WFRAG_OFF);

    cvt_feat_kernel<<<(NVOX * CTOT / 8 + 255) / 256, 256, 0, stream>>>(features, featH);
    cvt_w_kernel<<<(WFRAG_HALVES + 255) / 256, 256, 0, stream>>>(weight, wf);
    conv_main_kernel<<<NBLOCKS, 256, 0, stream>>>(featH, (const uint4*)wf, bias, nb, out);
}